// Round 18
// baseline (1045.344 us; speedup 1.0000x reference)
//
#include <hip/hip_runtime.h>
#include <math.h>

// ---- problem constants ----
#define CN 4
#define CC 256
#define CH 160
#define CW 160
#define SHH 40
#define SWW 40
#define CL 1600        // SHH*SWW
#define CSC 32
#define CS 64
#define NHEAD 32
#define INV_SCALE 0.17677669529663687f  // 1/sqrt(32)

typedef __attribute__((ext_vector_type(8))) short bf16x8;
typedef __attribute__((ext_vector_type(4))) float f32x4;

__device__ __forceinline__ int head_batch(int h) { return ((h >> 4) << 1) | ((h >> 3) & 1); }

// f32 -> bf16 with round-to-nearest-even
__device__ __forceinline__ short f2bf(float f)
{
    unsigned u = __float_as_uint(f);
    u += 0x7FFFu + ((u >> 16) & 1u);
    return (short)(u >> 16);
}

// np-style sum of squares over 32 elems (DECISION-CRITICAL: do not change)
__device__ __forceinline__ float norm32_np(const float* t)
{
    float lane[8];
    #pragma unroll
    for (int j = 0; j < 8; ++j) {
        float s = __fmul_rn(t[j], t[j]);
        s = __fadd_rn(s, __fmul_rn(t[j + 8], t[j + 8]));
        s = __fadd_rn(s, __fmul_rn(t[j + 16], t[j + 16]));
        s = __fadd_rn(s, __fmul_rn(t[j + 24], t[j + 24]));
        lane[j] = s;
    }
    float p01 = __fadd_rn(lane[0], lane[1]);
    float p23 = __fadd_rn(lane[2], lane[3]);
    float p45 = __fadd_rn(lane[4], lane[5]);
    float p67 = __fadd_rn(lane[6], lane[7]);
    return __fadd_rn(__fadd_rn(p01, p23), __fadd_rn(p45, p67));
}

// ============================================================
// 1) fused depthwise conv 4x4 stride4 + bias, and maxpool 4x4
//    (EXACT round-16 kernel — upstream bits frozen)
// ============================================================
__global__ __launch_bounds__(256)
void k_conv_pool(const float* __restrict__ x, const float* __restrict__ wdw,
                 const float* __restrict__ bdw,
                 float* __restrict__ dqn, float* __restrict__ dvn)
{
    int pix = blockIdx.x;            // ((n*40)+oh)*40+ow
    int c = threadIdx.x;
    int n = pix / CL;
    int r = pix - n * CL;
    int oh = r / SWW;
    int ow = r - oh * SWW;
    const float* xp = x + ((long)(n * CC + c) * CH + oh * 4) * CW + ow * 4;
    float4 w0 = *(const float4*)(wdw + c * 16);
    float4 w1 = *(const float4*)(wdw + c * 16 + 4);
    float4 w2 = *(const float4*)(wdw + c * 16 + 8);
    float4 w3 = *(const float4*)(wdw + c * 16 + 12);
    float4 r0 = *(const float4*)(xp);
    float4 r1 = *(const float4*)(xp + CW);
    float4 r2 = *(const float4*)(xp + 2 * CW);
    float4 r3 = *(const float4*)(xp + 3 * CW);
    float conv = r0.x * w0.x + r0.y * w0.y + r0.z * w0.z + r0.w * w0.w
               + r1.x * w1.x + r1.y * w1.y + r1.z * w1.z + r1.w * w1.w
               + r2.x * w2.x + r2.y * w2.y + r2.z * w2.z + r2.w * w2.w
               + r3.x * w3.x + r3.y * w3.y + r3.z * w3.z + r3.w * w3.w;
    conv += bdw[c];
    float mx = fmaxf(fmaxf(fmaxf(r0.x, r0.y), fmaxf(r0.z, r0.w)),
               fmaxf(fmaxf(fmaxf(r1.x, r1.y), fmaxf(r1.z, r1.w)),
               fmaxf(fmaxf(fmaxf(r2.x, r2.y), fmaxf(r2.z, r2.w)),
                     fmaxf(fmaxf(r3.x, r3.y), fmaxf(r3.z, r3.w)))));
    dqn[(long)pix * CC + c] = conv;
    dvn[(long)pix * CC + c] = mx;
}

// ============================================================
// 2) LayerNorm over C, in place. grid.y selects buffer.
//    (EXACT round-16 kernel — upstream bits frozen)
// ============================================================
__global__ __launch_bounds__(256)
void k_ln(float* __restrict__ b0, float* __restrict__ b1,
          const float* __restrict__ lnw, const float* __restrict__ lnb)
{
    float* buf = blockIdx.y ? b1 : b0;
    int row = blockIdx.x;
    int c = threadIdx.x;
    float v = buf[(long)row * CC + c];
    float s = v, s2 = v * v;
    #pragma unroll
    for (int off = 32; off >= 1; off >>= 1) {
        s += __shfl_xor(s, off);
        s2 += __shfl_xor(s2, off);
    }
    __shared__ float red[8];
    int wid = c >> 6, lane = c & 63;
    if (lane == 0) { red[wid * 2] = s; red[wid * 2 + 1] = s2; }
    __syncthreads();
    float ts = 0.f, ts2 = 0.f;
    #pragma unroll
    for (int w = 0; w < 4; ++w) { ts += red[w * 2]; ts2 += red[w * 2 + 1]; }
    float mu = ts * (1.0f / 256.0f);
    float var = ts2 * (1.0f / 256.0f) - mu * mu;
    float rstd = 1.0f / sqrtf(var + 1e-5f);
    buf[(long)row * CC + c] = (v - mu) * rstd * lnw[c] + lnb[c];
}

// ============================================================
// 3) 128x128 f32 GEMM, 8x8 register blocking (per-element chain =
//    ascending-k fused fma + one bias add — matches k_gemm256)
// ============================================================
__global__ __launch_bounds__(256)
void k_gemm_f32_128(const float* __restrict__ A, const float* __restrict__ Wt,
                    const float* __restrict__ bias, float* __restrict__ Cout,
                    int amode, int aplane)
{
    __shared__ float As[16][136];
    __shared__ float Bs[16][136];
    const int t = threadIdx.x;
    const int m0 = blockIdx.x * 128;
    const int n0 = blockIdx.y * 128;
    const int ty = t >> 4, tx = t & 15;
    float acc[8][8] = {};
    long abase = 0; int p0 = 0;
    if (amode == 1) {
        int nb = m0 / aplane;
        p0 = m0 - nb * aplane;
        abase = (long)nb * 256 * aplane;
    }
    for (int k0 = 0; k0 < 256; k0 += 16) {
        if (amode == 0) {
            int i = t >> 1, kq = (t & 1) * 8;
            const float* ap = A + (long)(m0 + i) * 256 + k0 + kq;
            float4 a1 = *(const float4*)ap;
            float4 a2 = *(const float4*)(ap + 4);
            As[kq + 0][i] = a1.x; As[kq + 1][i] = a1.y;
            As[kq + 2][i] = a1.z; As[kq + 3][i] = a1.w;
            As[kq + 4][i] = a2.x; As[kq + 5][i] = a2.y;
            As[kq + 6][i] = a2.z; As[kq + 7][i] = a2.w;
        } else {
            int j = t >> 4, i8 = (t & 15) * 8;
            const float* ap = A + abase + (long)(k0 + j) * aplane + p0 + i8;
            *(float4*)&As[j][i8]     = *(const float4*)ap;
            *(float4*)&As[j][i8 + 4] = *(const float4*)(ap + 4);
        }
        {
            int j = t >> 4, n8 = (t & 15) * 8;
            const float* bp = Wt + (long)(k0 + j) * 256 + n0 + n8;
            *(float4*)&Bs[j][n8]     = *(const float4*)bp;
            *(float4*)&Bs[j][n8 + 4] = *(const float4*)(bp + 4);
        }
        __syncthreads();
        #pragma unroll
        for (int k = 0; k < 16; ++k) {
            float4 a1 = *(const float4*)&As[k][ty * 8];
            float4 a2 = *(const float4*)&As[k][ty * 8 + 4];
            float4 b1 = *(const float4*)&Bs[k][tx * 8];
            float4 b2 = *(const float4*)&Bs[k][tx * 8 + 4];
            float aa[8] = {a1.x, a1.y, a1.z, a1.w, a2.x, a2.y, a2.z, a2.w};
            float bb[8] = {b1.x, b1.y, b1.z, b1.w, b2.x, b2.y, b2.z, b2.w};
            #pragma unroll
            for (int ii = 0; ii < 8; ++ii)
                #pragma unroll
                for (int jj = 0; jj < 8; ++jj)
                    acc[ii][jj] = fmaf(aa[ii], bb[jj], acc[ii][jj]);
        }
        __syncthreads();
    }
    int colb = n0 + tx * 8;
    float4 bi1 = *(const float4*)(bias + colb);
    float4 bi2 = *(const float4*)(bias + colb + 4);
    float bias8[8] = {bi1.x, bi1.y, bi1.z, bi1.w, bi2.x, bi2.y, bi2.z, bi2.w};
    #pragma unroll
    for (int ii = 0; ii < 8; ++ii) {
        long mrow = m0 + ty * 8 + ii;
        float4 o1, o2;
        o1.x = acc[ii][0] + bias8[0];
        o1.y = acc[ii][1] + bias8[1];
        o1.z = acc[ii][2] + bias8[2];
        o1.w = acc[ii][3] + bias8[3];
        o2.x = acc[ii][4] + bias8[4];
        o2.y = acc[ii][5] + bias8[5];
        o2.z = acc[ii][6] + bias8[6];
        o2.w = acc[ii][7] + bias8[7];
        *(float4*)(Cout + mrow * 256 + colb) = o1;
        *(float4*)(Cout + mrow * 256 + colb + 4) = o2;
    }
}

// ============================================================
// 4) generic 64-tile f32 GEMM (kept for am: omode=1, M=6400)
// ============================================================
#define GBK 16
#define GSTR 68
__global__ __launch_bounds__(256)
void k_gemm256(const float* __restrict__ A, const float* __restrict__ Wt,
               const float* __restrict__ bias, float* __restrict__ Cout,
               int M, int amode, int aplane,
               int omode, int oplane, long obstride, int ocoff)
{
    __shared__ float As[GBK][GSTR];
    __shared__ float Bs[GBK][GSTR];
    const int t = threadIdx.x;
    const int m0 = blockIdx.x * 64;
    const int n0 = blockIdx.y * 64;
    const int ty = t >> 4, tx = t & 15;
    float acc[4][4] = {};
    long abase = 0; int p0 = 0;
    if (amode == 1) {
        int nb = m0 / aplane;
        p0 = m0 - nb * aplane;
        abase = (long)nb * 256 * aplane;
    }
    for (int k0 = 0; k0 < 256; k0 += GBK) {
        if (amode == 0) {
            int i = t >> 2, j4 = (t & 3) * 4;
            float4 a = *(const float4*)(A + (long)(m0 + i) * 256 + k0 + j4);
            As[j4 + 0][i] = a.x; As[j4 + 1][i] = a.y;
            As[j4 + 2][i] = a.z; As[j4 + 3][i] = a.w;
        } else {
            int j = t >> 4, i4 = (t & 15) * 4;
            float4 a = *(const float4*)(A + abase + (long)(k0 + j) * aplane + p0 + i4);
            *(float4*)&As[j][i4] = a;
        }
        {
            int k = t >> 4, n4 = (t & 15) * 4;
            float4 b = *(const float4*)(Wt + (long)(k0 + k) * 256 + n0 + n4);
            *(float4*)&Bs[k][n4] = b;
        }
        __syncthreads();
        #pragma unroll
        for (int k = 0; k < GBK; ++k) {
            float4 a = *(const float4*)&As[k][ty * 4];
            float4 b = *(const float4*)&Bs[k][tx * 4];
            float aa[4] = {a.x, a.y, a.z, a.w};
            float bb[4] = {b.x, b.y, b.z, b.w};
            #pragma unroll
            for (int ii = 0; ii < 4; ++ii)
                #pragma unroll
                for (int jj = 0; jj < 4; ++jj)
                    acc[ii][jj] = fmaf(aa[ii], bb[jj], acc[ii][jj]);
        }
        __syncthreads();
    }
    int colb = n0 + tx * 4;
    float4 bi = *(const float4*)(bias + colb);
    float bias4[4] = {bi.x, bi.y, bi.z, bi.w};
    if (omode == 0) {
        #pragma unroll
        for (int ii = 0; ii < 4; ++ii) {
            long mrow = m0 + ty * 4 + ii;
            float4 o;
            o.x = acc[ii][0] + bias4[0];
            o.y = acc[ii][1] + bias4[1];
            o.z = acc[ii][2] + bias4[2];
            o.w = acc[ii][3] + bias4[3];
            *(float4*)(Cout + mrow * 256 + colb) = o;
        }
    } else {
        int nb2 = m0 / oplane;
        #pragma unroll
        for (int ii = 0; ii < 4; ++ii) {
            int mrow = m0 + ty * 4 + ii;
            int p = mrow - nb2 * oplane;
            #pragma unroll
            for (int jj = 0; jj < 4; ++jj)
                Cout[(long)nb2 * obstride + (long)(ocoff + colb + jj) * oplane + p]
                    = acc[ii][jj] + bias4[jj];
        }
    }
}

// ============================================================
// 5) anchors: np-ordered 5x5 block mean (DECISION-CRITICAL)
// ============================================================
__global__ __launch_bounds__(256)
void k_anchor(const float* __restrict__ dq, const float* __restrict__ dv,
              float* __restrict__ ancq, float* __restrict__ ancv)
{
    int bs = blockIdx.x;   // b*64+s
    int c = threadIdx.x;
    int b = bs >> 6, s = bs & 63;
    int ai = s >> 3, aj = s & 7;
    float colq[5], colv[5];
    #pragma unroll
    for (int dj = 0; dj < 5; ++dj) {
        long pix0 = (long)b * CL + (ai * 5) * SWW + aj * 5 + dj;
        float cq = dq[pix0 * CC + c];
        float cv = dv[pix0 * CC + c];
        #pragma unroll
        for (int di = 1; di < 5; ++di) {
            long pix = pix0 + (long)di * SWW;
            cq = __fadd_rn(cq, dq[pix * CC + c]);
            cv = __fadd_rn(cv, dv[pix * CC + c]);
        }
        colq[dj] = cq; colv[dj] = cv;
    }
    float sq = colq[0], sv = colv[0];
    #pragma unroll
    for (int dj = 1; dj < 5; ++dj) {
        sq = __fadd_rn(sq, colq[dj]);
        sv = __fadd_rn(sv, colv[dj]);
    }
    ancq[(long)bs * CC + c] = sq / 25.0f;
    ancv[(long)bs * CC + c] = sv / 25.0f;
}

// ============================================================
// 6) attention v4 (unchanged from round 16)
// ============================================================
__global__ __launch_bounds__(256)
void k_attn(const float* __restrict__ dq, const float* __restrict__ dv,
            float* __restrict__ att4)
{
    __shared__ float Kl[64][36];
    __shared__ float Vl[64][36];
    int qt = blockIdx.x;     // 0..24  (64 q-rows each)
    int h = blockIdx.y;      // 0..31
    int b = head_batch(h), fc = h & 7;
    int pb = b ^ 2;
    int t = threadIdx.x;
    int qa = t >> 3, part = t & 7;
    int lane = t & 63;
    int qrow0 = qt * 64 + qa;
    int qrow1 = qrow0 + 32;

    float qreg0[32], qreg1[32];
    {
        const float4* qp0 = (const float4*)(dq + (long)(b * CL + qrow0) * CC + fc * CSC);
        const float4* qp1 = (const float4*)(dq + (long)(b * CL + qrow1) * CC + fc * CSC);
        #pragma unroll
        for (int j8 = 0; j8 < 8; ++j8) {
            float4 f0 = qp0[j8], f1 = qp1[j8];
            qreg0[4 * j8 + 0] = f0.x; qreg0[4 * j8 + 1] = f0.y;
            qreg0[4 * j8 + 2] = f0.z; qreg0[4 * j8 + 3] = f0.w;
            qreg1[4 * j8 + 0] = f1.x; qreg1[4 * j8 + 1] = f1.y;
            qreg1[4 * j8 + 2] = f1.z; qreg1[4 * j8 + 3] = f1.w;
        }
    }
    float Oa0[4] = {0, 0, 0, 0}, Oa1[4] = {0, 0, 0, 0};
    float mr0 = -INFINITY, lr0 = 0.f;
    float mr1 = -INFINITY, lr1 = 0.f;

    int li = t >> 2, lp = t & 3;
    float4 kA, kB, vA, vB;
    {
        const float* kp = dq + (long)(pb * CL + li) * CC + fc * CSC + lp * 8;
        const float* vp = dv + (long)(pb * CL + li) * CC + fc * CSC + lp * 8;
        kA = *(const float4*)kp; kB = *(const float4*)(kp + 4);
        vA = *(const float4*)vp; vB = *(const float4*)(vp + 4);
    }

    for (int kt = 0; kt < 25; ++kt) {
        *(float4*)&Kl[li][lp * 8]     = kA;
        *(float4*)&Kl[li][lp * 8 + 4] = kB;
        *(float4*)&Vl[li][lp * 8]     = vA;
        *(float4*)&Vl[li][lp * 8 + 4] = vB;
        __syncthreads();
        if (kt + 1 < 25) {
            const float* kp = dq + (long)(pb * CL + (kt + 1) * 64 + li) * CC + fc * CSC + lp * 8;
            const float* vp = dv + (long)(pb * CL + (kt + 1) * 64 + li) * CC + fc * CSC + lp * 8;
            kA = *(const float4*)kp; kB = *(const float4*)(kp + 4);
            vA = *(const float4*)vp; vB = *(const float4*)(vp + 4);
        }
        float sc0[8], sc1[8];
        float tmax0 = -INFINITY, tmax1 = -INFINITY;
        #pragma unroll
        for (int si = 0; si < 8; ++si) {
            int s = si * 8 + part;
            const float4* kr = (const float4*)&Kl[s][0];
            float d0 = 0.f, d1 = 0.f;
            #pragma unroll
            for (int j8 = 0; j8 < 8; ++j8) {
                float4 k4 = kr[j8];
                d0 = fmaf(qreg0[4 * j8 + 0], k4.x, d0);
                d0 = fmaf(qreg0[4 * j8 + 1], k4.y, d0);
                d0 = fmaf(qreg0[4 * j8 + 2], k4.z, d0);
                d0 = fmaf(qreg0[4 * j8 + 3], k4.w, d0);
                d1 = fmaf(qreg1[4 * j8 + 0], k4.x, d1);
                d1 = fmaf(qreg1[4 * j8 + 1], k4.y, d1);
                d1 = fmaf(qreg1[4 * j8 + 2], k4.z, d1);
                d1 = fmaf(qreg1[4 * j8 + 3], k4.w, d1);
            }
            d0 *= INV_SCALE; d1 *= INV_SCALE;
            sc0[si] = d0; sc1[si] = d1;
            tmax0 = fmaxf(tmax0, d0);
            tmax1 = fmaxf(tmax1, d1);
        }
        tmax0 = fmaxf(tmax0, __shfl_xor(tmax0, 1));
        tmax0 = fmaxf(tmax0, __shfl_xor(tmax0, 2));
        tmax0 = fmaxf(tmax0, __shfl_xor(tmax0, 4));
        tmax1 = fmaxf(tmax1, __shfl_xor(tmax1, 1));
        tmax1 = fmaxf(tmax1, __shfl_xor(tmax1, 2));
        tmax1 = fmaxf(tmax1, __shfl_xor(tmax1, 4));
        float mnew0 = fmaxf(mr0, tmax0);
        float mnew1 = fmaxf(mr1, tmax1);
        float corr0 = expf(mr0 - mnew0);
        float corr1 = expf(mr1 - mnew1);
        float wexp0[8], wexp1[8];
        float psum0 = 0.f, psum1 = 0.f;
        #pragma unroll
        for (int si = 0; si < 8; ++si) {
            wexp0[si] = expf(sc0[si] - mnew0);
            psum0 += wexp0[si];
            wexp1[si] = expf(sc1[si] - mnew1);
            psum1 += wexp1[si];
        }
        psum0 += __shfl_xor(psum0, 1);
        psum0 += __shfl_xor(psum0, 2);
        psum0 += __shfl_xor(psum0, 4);
        psum1 += __shfl_xor(psum1, 1);
        psum1 += __shfl_xor(psum1, 2);
        psum1 += __shfl_xor(psum1, 4);
        lr0 = lr0 * corr0 + psum0;
        lr1 = lr1 * corr1 + psum1;
        #pragma unroll
        for (int j = 0; j < 4; ++j) { Oa0[j] *= corr0; Oa1[j] *= corr1; }
        int lbase = lane & ~7;
        #pragma unroll
        for (int si = 0; si < 8; ++si) {
            #pragma unroll
            for (int p8 = 0; p8 < 8; ++p8) {
                int s = si * 8 + p8;
                float w0 = __shfl(wexp0[si], lbase | p8, 64);
                float w1 = __shfl(wexp1[si], lbase | p8, 64);
                const float4 v4 = *(const float4*)&Vl[s][part * 4];
                Oa0[0] = fmaf(w0, v4.x, Oa0[0]);
                Oa0[1] = fmaf(w0, v4.y, Oa0[1]);
                Oa0[2] = fmaf(w0, v4.z, Oa0[2]);
                Oa0[3] = fmaf(w0, v4.w, Oa0[3]);
                Oa1[0] = fmaf(w1, v4.x, Oa1[0]);
                Oa1[1] = fmaf(w1, v4.y, Oa1[1]);
                Oa1[2] = fmaf(w1, v4.z, Oa1[2]);
                Oa1[3] = fmaf(w1, v4.w, Oa1[3]);
            }
        }
        mr0 = mnew0; mr1 = mnew1;
        __syncthreads();
    }
    float inv0 = 1.0f / lr0;
    float inv1 = 1.0f / lr1;
    float* op0 = att4 + (long)(b * CL + qrow0) * CC + fc * CSC + part * 4;
    float* op1 = att4 + (long)(b * CL + qrow1) * CC + fc * CSC + part * 4;
    float4 o0, o1;
    o0.x = Oa0[0] * inv0; o0.y = Oa0[1] * inv0; o0.z = Oa0[2] * inv0; o0.w = Oa0[3] * inv0;
    o1.x = Oa1[0] * inv1; o1.y = Oa1[1] * inv1; o1.z = Oa1[2] * inv1; o1.w = Oa1[3] * inv1;
    *(float4*)op0 = o0;
    *(float4*)op1 = o1;
}

// ============================================================
// 7) bilinear x4 upsample -> out[:, 0:256]
// ============================================================
__global__ __launch_bounds__(256)
void k_resize(const float* __restrict__ am, float* __restrict__ out)
{
    int plane = blockIdx.y;                       // n*256 + c
    int o = blockIdx.x * 256 + threadIdx.x;       // 0..25599
    int y = o / CW, xx = o - y * CW;
    const float* src = am + (long)plane * (SHH * SWW);
    float fy = (y + 0.5f) * 0.25f - 0.5f;
    int iy0 = (int)floorf(fy);
    float wy = fy - iy0;
    int iy1 = min(iy0 + 1, SHH - 1); iy0 = max(iy0, 0);
    float fx = (xx + 0.5f) * 0.25f - 0.5f;
    int ix0 = (int)floorf(fx);
    float wx = fx - ix0;
    int ix1 = min(ix0 + 1, SWW - 1); ix0 = max(ix0, 0);
    float v00 = src[iy0 * SWW + ix0], v01 = src[iy0 * SWW + ix1];
    float v10 = src[iy1 * SWW + ix0], v11 = src[iy1 * SWW + ix1];
    float v = (1.f - wy) * ((1.f - wx) * v00 + wx * v01)
            + wy * ((1.f - wx) * v10 + wx * v11);
    int n = plane >> 8, c = plane & 255;
    out[((long)(n * 512 + c)) * (CH * CW) + o] = v;
}

// ============================================================
// 8) precompute np-normalized anchor rows per head (DECISION-CRITICAL)
// ============================================================
__global__ __launch_bounds__(64)
void k_aqkn_np(const float* __restrict__ ancq, float* __restrict__ aqkn)
{
    int h = blockIdx.x, s = threadIdx.x;
    int b = head_batch(h), fc = h & 7;
    const float* p = ancq + (long)(b * CS + s) * CC + fc * CSC;
    float a[32];
    #pragma unroll
    for (int d = 0; d < 32; ++d) a[d] = p[d];
    float anorm = fmaxf(sqrtf(norm32_np(a)), 1e-12f);
    #pragma unroll
    for (int d = 0; d < 32; ++d) aqkn[(long)(h * CS + s) * CSC + d] = a[d] / anorm;
}

// ============================================================
// 9) routing-1 lite (DECISION-CRITICAL per-chain order)
// ============================================================
__global__ __launch_bounds__(256)
void k_routing1_lite(const float* __restrict__ dq, const float* __restrict__ aqkn,
                     const float* __restrict__ dalpha, const float* __restrict__ dbeta,
                     float* __restrict__ valb, int* __restrict__ idxb)
{
    __shared__ float An[CS * CSC];   // 8 KB
    int h = blockIdx.y;
    int b = head_batch(h), fc = h & 7;
    int t = threadIdx.x;
    for (int u = t; u < CS * CSC; u += 256) An[u] = aqkn[(long)h * CS * CSC + u];
    __syncthreads();
    int l = blockIdx.x * 256 + t;
    if (l >= CL) return;
    float da = dalpha[0], db = dbeta[0];
    const float* qp = dq + (long)(b * CL + l) * CC + fc * CSC;
    float q[32];
    #pragma unroll
    for (int d = 0; d < 32; ++d) q[d] = qp[d];
    float qnorm = fmaxf(sqrtf(norm32_np(q)), 1e-12f);
    float qn[32];
    #pragma unroll
    for (int d = 0; d < 32; ++d) qn[d] = q[d] / qnorm;
    float best = -1.f; int bi = 0;
    for (int sg = 0; sg < CS; sg += 4) {
        float acc[4];
        #pragma unroll
        for (int i = 0; i < 4; ++i) {
            const float4 a0 = *(const float4*)&An[(sg + i) * CSC];
            acc[i] = __fmul_rn(qn[0], a0.x);
            acc[i] = __fadd_rn(acc[i], __fmul_rn(qn[1], a0.y));
            acc[i] = __fadd_rn(acc[i], __fmul_rn(qn[2], a0.z));
            acc[i] = __fadd_rn(acc[i], __fmul_rn(qn[3], a0.w));
        }
        #pragma unroll
        for (int dg = 1; dg < 8; ++dg) {
            #pragma unroll
            for (int i = 0; i < 4; ++i) {
                const float4 a4 = *(const float4*)&An[(sg + i) * CSC + dg * 4];
                acc[i] = __fadd_rn(acc[i], __fmul_rn(qn[4 * dg + 0], a4.x));
                acc[i] = __fadd_rn(acc[i], __fmul_rn(qn[4 * dg + 1], a4.y));
                acc[i] = __fadd_rn(acc[i], __fmul_rn(qn[4 * dg + 2], a4.z));
                acc[i] = __fadd_rn(acc[i], __fmul_rn(qn[4 * dg + 3], a4.w));
            }
        }
        #pragma unroll
        for (int i = 0; i < 4; ++i) {
            float tv = __fadd_rn(__fmul_rn(da, acc[i]), db);
            float sim = 1.0f / (1.0f + expf(-tv));
            if (sim > best) { best = sim; bi = sg + i; }
        }
    }
    valb[h * CL + l] = best;
    idxb[h * CL + l] = bi;
}

// ============================================================
// 10) deterministic scatter (DECISION/VALUE path)
// ============================================================
__global__ __launch_bounds__(64)
void k_scatter(const float* __restrict__ dq, const float* __restrict__ dv,
               const float* __restrict__ ancq, const float* __restrict__ ancv,
               const float* __restrict__ valb, const int* __restrict__ idxb,
               float* __restrict__ agg)
{
    int cl = blockIdx.x;
    int h = cl >> 6, s = cl & 63;
    int b = head_batch(h), fc = h & 7;
    int j = threadIdx.x;
    const float* base = (j < 32) ? (dq + (long)b * CL * CC + fc * CSC + j)
                                 : (dv + (long)b * CL * CC + fc * CSC + (j - 32));
    float init = (j < 32) ? ancq[(long)(b * CS + s) * CC + fc * CSC + j]
                          : ancv[(long)(b * CS + s) * CC + fc * CSC + (j - 32)];
    float acc = init, cnt = 1.0f;
    const int* ix = idxb + h * CL;
    const float* vb = valb + h * CL;
    for (int l = 0; l < CL; ++l) {
        if (ix[l] == s) {
            float v = vb[l];
            acc = __fadd_rn(acc, __fmul_rn(v, base[(long)l * CC]));
            cnt = __fadd_rn(cnt, v);
        }
    }
    agg[(long)cl * 65 + j] = acc;
    if (j == 0) agg[(long)cl * 65 + 64] = cnt;
}

// ============================================================
// 11) finalize (DECISION-CRITICAL)
// ============================================================
__global__ __launch_bounds__(64)
void k_finalize(const float* __restrict__ agg, float* __restrict__ apn,
                float* __restrict__ avo)
{
    int h = blockIdx.x, s = threadIdx.x;
    int sh_ = h ^ 16;
    const float* r = agg + (long)(sh_ * CS + s) * 65;
    float cnt = r[64];
    float a[32];
    #pragma unroll
    for (int d = 0; d < 32; ++d) a[d] = r[d] / cnt;
    float nrm = fmaxf(sqrtf(norm32_np(a)), 1e-12f);
    long o = (long)(h * CS + s) * CSC;
    #pragma unroll
    for (int d = 0; d < 32; ++d) {
        apn[o + d] = a[d] / nrm;
        avo[o + d] = r[32 + d] / cnt;
    }
}

// ============================================================
// 12) routing-2 lite (DECISION-CRITICAL per-chain order)
// ============================================================
__global__ __launch_bounds__(512)
void k_routing2_lite(float* __restrict__ xp, const float* __restrict__ apn,
                     const float* __restrict__ avv,
                     const float* __restrict__ alpha_, const float* __restrict__ beta_)
{
    __shared__ float Anl[16384];   // [s][dg][fc][4]  64 KB
    int blk = blockIdx.x;          // 1600
    int b = blk / 400;
    int p0 = (blk % 400) * 64;
    int t = threadIdx.x;
    int pi = t >> 3, fc = t & 7;
    int p = p0 + pi;
    int hb0 = ((b >> 1) << 4) | ((b & 1) << 3);
    float al = alpha_[0], be = beta_[0];
    for (int u = t; u < 16384; u += 512) {
        int fci = u >> 11, s = (u >> 5) & 63, d = u & 31;
        Anl[((s * 8 + (d >> 2)) * 8 + fci) * 4 + (d & 3)] = apn[(long)hb0 * 2048 + u];
    }
    __syncthreads();
    float* xr = xp + ((long)b * 25600 + p) * CC + fc * CSC;
    float q[32];
    #pragma unroll
    for (int j8 = 0; j8 < 8; ++j8) {
        float4 f = ((const float4*)xr)[j8];
        q[4 * j8 + 0] = f.x; q[4 * j8 + 1] = f.y;
        q[4 * j8 + 2] = f.z; q[4 * j8 + 3] = f.w;
    }
    float qnorm = fmaxf(sqrtf(norm32_np(q)), 1e-12f);
    float qn[32];
    #pragma unroll
    for (int d = 0; d < 32; ++d) qn[d] = q[d] / qnorm;

    float best = -1.f; int bi = 0;
    for (int sg = 0; sg < CS; sg += 4) {
        float acc[4];
        #pragma unroll
        for (int i = 0; i < 4; ++i) {
            const float4 a0 = *(const float4*)&Anl[(((sg + i) * 8 + 0) * 8 + fc) * 4];
            acc[i] = __fmul_rn(qn[0], a0.x);
            acc[i] = __fadd_rn(acc[i], __fmul_rn(qn[1], a0.y));
            acc[i] = __fadd_rn(acc[i], __fmul_rn(qn[2], a0.z));
            acc[i] = __fadd_rn(acc[i], __fmul_rn(qn[3], a0.w));
        }
        #pragma unroll
        for (int dg = 1; dg < 8; ++dg) {
            #pragma unroll
            for (int i = 0; i < 4; ++i) {
                const float4 a4 = *(const float4*)&Anl[(((sg + i) * 8 + dg) * 8 + fc) * 4];
                acc[i] = __fadd_rn(acc[i], __fmul_rn(qn[4 * dg + 0], a4.x));
                acc[i] = __fadd_rn(acc[i], __fmul_rn(qn[4 * dg + 1], a4.y));
                acc[i] = __fadd_rn(acc[i], __fmul_rn(qn[4 * dg + 2], a4.z));
                acc[i] = __fadd_rn(acc[i], __fmul_rn(qn[4 * dg + 3], a4.w));
            }
        }
        #pragma unroll
        for (int i = 0; i < 4; ++i) {
            float tv = __fadd_rn(__fmul_rn(al, acc[i]), be);
            float sim = 1.0f / (1.0f + expf(-tv));
            if (sim > best) { best = sim; bi = sg + i; }
        }
    }
    const float* av = avv + ((long)(hb0 + fc) * CS + bi) * CSC;
    #pragma unroll
    for (int d = 0; d < 32; ++d) xr[d] = __fmul_rn(best, av[d]);
}

// ============================================================
// 13) w_m1 -> bf16 transposed [n][k] (one-time, tiny)
// ============================================================
__global__ __launch_bounds__(256)
void k_wm1t_bf16(const float* __restrict__ wm1, short* __restrict__ wt)
{
    int n = blockIdx.x;       // 256
    int k = threadIdx.x;      // 256
    wt[n * 256 + k] = f2bf(wm1[k * 256 + n]);
}

// ============================================================
// 14) final coc GEMM in bf16 MFMA (tolerance path)
// ============================================================
__global__ __launch_bounds__(256)
void k_gemm_bf16_final(const float* __restrict__ coc, const short* __restrict__ wt,
                       const float* __restrict__ bias, float* __restrict__ out)
{
    __shared__ short As[64][40];
    __shared__ short Bs[64][40];
    const int t = threadIdx.x;
    const int m0 = blockIdx.x * 64;
    const int n0 = blockIdx.y * 64;
    const int nb = m0 / 25600;
    const int p0 = m0 - nb * 25600;
    const int w = t >> 6;
    const int l = t & 63;
    const int lr = l & 15, lk = l >> 4;

    f32x4 acc[4] = {};
    for (int k0 = 0; k0 < 256; k0 += 32) {
        {
            int row = t >> 2, kq = (t & 3) * 8;
            const float* ap = coc + (long)(m0 + row) * 256 + k0 + kq;
            float4 a1 = *(const float4*)ap;
            float4 a2 = *(const float4*)(ap + 4);
            bf16x8 v;
            v[0] = f2bf(a1.x); v[1] = f2bf(a1.y); v[2] = f2bf(a1.z); v[3] = f2bf(a1.w);
            v[4] = f2bf(a2.x); v[5] = f2bf(a2.y); v[6] = f2bf(a2.z); v[7] = f2bf(a2.w);
            *(bf16x8*)&As[row][kq] = v;
        }
        {
            int col = t >> 2, kq = (t & 3) * 8;
            bf16x8 v = *(const bf16x8*)&wt[(n0 + col) * 256 + k0 + kq];
            *(bf16x8*)&Bs[col][kq] = v;
        }
        __syncthreads();
        bf16x8 af = *(const bf16x8*)&As[w * 16 + lr][lk * 8];
        #pragma unroll
        for (int c = 0; c < 4; ++c) {
            bf16x8 bfv = *(const bf16x8*)&Bs[c * 16 + lr][lk * 8];
            acc[c] = __builtin_amdgcn_mfma_f32_16x16x32_bf16(af, bfv, acc[c], 0, 0, 0);
        }
        __syncthreads();
    }
    #pragma unroll
    for (int c = 0; c < 4; ++c) {
        int col = n0 + c * 16 + lr;
        float bv = bias[col];
        #pragma unroll
        for (int r = 0; r < 4; ++r) {
            int p = p0 + w * 16 + lk * 4 + r;
            out[(long)nb * 13107200 + (long)(256 + col) * 25600 + p] = acc[c][r] + bv;
        }
    }
}

// ============================================================
// launcher
// ============================================================
extern "C" void kernel_launch(void* const* d_in, const int* in_sizes, int n_in,
                              void* d_out, int out_size, void* d_ws, size_t ws_size,
                              hipStream_t stream)
{
    const float* x      = (const float*)d_in[0];
    const float* wdw    = (const float*)d_in[1];
    const float* bdw    = (const float*)d_in[2];
    const float* lnw    = (const float*)d_in[3];
    const float* lnb    = (const float*)d_in[4];
    const float* wqk    = (const float*)d_in[5];
    const float* bqk    = (const float*)d_in[6];
    const float* wv     = (const float*)d_in[7];
    const float* bv     = (const float*)d_in[8];
    const float* wpoint = (const float*)d_in[9];
    const float* bpoint = (const float*)d_in[10];
    const float* dalpha = (const float*)d_in[11];
    const float* dbeta  = (const float*)d_in[12];
    const float* alpha_ = (const float*)d_in[13];
    const float* beta_  = (const float*)d_in[14];
    const float* wm0    = (const float*)d_in[15];
    const float* bm0    = (const float*)d_in[16];
    const float* wm1    = (const float*)d_in[17];
    const float* bm1    = (const float*)d_in[18];
    float* out = (float*)d_out;
    float* ws = (float*)d_ws;

    float* dqn  = ws;                 // 1,638,400
    float* dvn  = ws + 1638400;       // 1,638,400
    float* dq   = ws + 3276800;       // 1,638,400
    float* dv   = ws + 4915200;       // 1,638,400
    float* ancq = ws + 6553600;       // 65,536
    float* ancv = ws + 6619136;       // 65,536
    float* aqkn = ws + 6684672;       // 65,536
    float* agg  = ws + 6750208;       // 133,120
    float* apn  = ws + 6883328;       // 65,536
    float* avv  = ws + 6948864;       // 65,536
    float* valb = ws + 7014400;       // 51,200
    int*   idxb = (int*)(ws + 7065600); // 51,200
    short* wt   = (short*)(ws + 7116800); // 65,536 shorts
    float* xp   = ws + 7149568;       // 26,214,400  (becomes coc in place)
    float* att4 = dqn;                // reuse after dq GEMM consumed dqn
    float* am   = dvn;                // reuse after dv GEMM consumed dvn

    // --- shared upstream (conv/LN exactly as round 16) ---
    k_conv_pool<<<dim3(CN * CL), dim3(256), 0, stream>>>(x, wdw, bdw, dqn, dvn);
    k_ln<<<dim3(CN * CL, 2), dim3(256), 0, stream>>>(dqn, dvn, lnw, lnb);
    k_gemm_f32_128<<<dim3(50, 2), dim3(256), 0, stream>>>(dqn, wqk, bqk, dq, 0, 0);
    k_gemm_f32_128<<<dim3(50, 2), dim3(256), 0, stream>>>(dvn, wv,  bv,  dv, 0, 0);
    k_anchor<<<dim3(CN * CS), dim3(256), 0, stream>>>(dq, dv, ancq, ancv);

    // --- att half ---
    k_attn<<<dim3(25, NHEAD), dim3(256), 0, stream>>>(dq, dv, att4);
    k_gemm256<<<dim3(100, 4), dim3(256), 0, stream>>>(att4, wm0, bm0, am, 6400, 0, 0,
                                                      1, 1600, 409600L, 0);
    k_resize<<<dim3(100, CN * 256), dim3(256), 0, stream>>>(am, out);

    // --- coc half (np-matched decision arithmetic) ---
    k_aqkn_np<<<dim3(NHEAD), dim3(64), 0, stream>>>(ancq, aqkn);
    k_routing1_lite<<<dim3(7, NHEAD), dim3(256), 0, stream>>>(dq, aqkn, dalpha, dbeta,
                                                              valb, idxb);
    k_scatter<<<dim3(2048), dim3(64), 0, stream>>>(dq, dv, ancq, ancv, valb, idxb, agg);
    k_finalize<<<dim3(NHEAD), dim3(64), 0, stream>>>(agg, apn, avv);
    k_gemm_f32_128<<<dim3(800, 2), dim3(256), 0, stream>>>(x, wpoint, bpoint, xp, 1, 25600);
    k_routing2_lite<<<dim3(1600), dim3(512), 0, stream>>>(xp, apn, avv, alpha_, beta_);
    k_wm1t_bf16<<<dim3(256), dim3(256), 0, stream>>>(wm1, wt);
    k_gemm_bf16_final<<<dim3(1600, 4), dim3(256), 0, stream>>>(xp, wt, bm1, out);
}

// Round 19
// 981.892 us; speedup vs baseline: 1.0646x; 1.0646x over previous
//
#include <hip/hip_runtime.h>
#include <math.h>

// ---- problem constants ----
#define CN 4
#define CC 256
#define CH 160
#define CW 160
#define SHH 40
#define SWW 40
#define CL 1600        // SHH*SWW
#define CSC 32
#define CS 64
#define NHEAD 32
#define INV_SCALE 0.17677669529663687f  // 1/sqrt(32)

typedef __attribute__((ext_vector_type(8))) short bf16x8;
typedef __attribute__((ext_vector_type(4))) float f32x4;

__device__ __forceinline__ int head_batch(int h) { return ((h >> 4) << 1) | ((h >> 3) & 1); }

// f32 -> bf16 with round-to-nearest-even
__device__ __forceinline__ short f2bf(float f)
{
    unsigned u = __float_as_uint(f);
    u += 0x7FFFu + ((u >> 16) & 1u);
    return (short)(u >> 16);
}

// np-style sum of squares over 32 elems (DECISION-CRITICAL: do not change)
__device__ __forceinline__ float norm32_np(const float* t)
{
    float lane[8];
    #pragma unroll
    for (int j = 0; j < 8; ++j) {
        float s = __fmul_rn(t[j], t[j]);
        s = __fadd_rn(s, __fmul_rn(t[j + 8], t[j + 8]));
        s = __fadd_rn(s, __fmul_rn(t[j + 16], t[j + 16]));
        s = __fadd_rn(s, __fmul_rn(t[j + 24], t[j + 24]));
        lane[j] = s;
    }
    float p01 = __fadd_rn(lane[0], lane[1]);
    float p23 = __fadd_rn(lane[2], lane[3]);
    float p45 = __fadd_rn(lane[4], lane[5]);
    float p67 = __fadd_rn(lane[6], lane[7]);
    return __fadd_rn(__fadd_rn(p01, p23), __fadd_rn(p45, p67));
}

// ============================================================
// 1) fused depthwise conv 4x4 stride4 + bias, and maxpool 4x4
//    (frozen upstream kernel)
// ============================================================
__global__ __launch_bounds__(256)
void k_conv_pool(const float* __restrict__ x, const float* __restrict__ wdw,
                 const float* __restrict__ bdw,
                 float* __restrict__ dqn, float* __restrict__ dvn)
{
    int pix = blockIdx.x;            // ((n*40)+oh)*40+ow
    int c = threadIdx.x;
    int n = pix / CL;
    int r = pix - n * CL;
    int oh = r / SWW;
    int ow = r - oh * SWW;
    const float* xp = x + ((long)(n * CC + c) * CH + oh * 4) * CW + ow * 4;
    float4 w0 = *(const float4*)(wdw + c * 16);
    float4 w1 = *(const float4*)(wdw + c * 16 + 4);
    float4 w2 = *(const float4*)(wdw + c * 16 + 8);
    float4 w3 = *(const float4*)(wdw + c * 16 + 12);
    float4 r0 = *(const float4*)(xp);
    float4 r1 = *(const float4*)(xp + CW);
    float4 r2 = *(const float4*)(xp + 2 * CW);
    float4 r3 = *(const float4*)(xp + 3 * CW);
    float conv = r0.x * w0.x + r0.y * w0.y + r0.z * w0.z + r0.w * w0.w
               + r1.x * w1.x + r1.y * w1.y + r1.z * w1.z + r1.w * w1.w
               + r2.x * w2.x + r2.y * w2.y + r2.z * w2.z + r2.w * w2.w
               + r3.x * w3.x + r3.y * w3.y + r3.z * w3.z + r3.w * w3.w;
    conv += bdw[c];
    float mx = fmaxf(fmaxf(fmaxf(r0.x, r0.y), fmaxf(r0.z, r0.w)),
               fmaxf(fmaxf(fmaxf(r1.x, r1.y), fmaxf(r1.z, r1.w)),
               fmaxf(fmaxf(fmaxf(r2.x, r2.y), fmaxf(r2.z, r2.w)),
                     fmaxf(fmaxf(r3.x, r3.y), fmaxf(r3.z, r3.w)))));
    dqn[(long)pix * CC + c] = conv;
    dvn[(long)pix * CC + c] = mx;
}

// ============================================================
// 2) LayerNorm over C, in place. grid.y selects buffer. (frozen)
// ============================================================
__global__ __launch_bounds__(256)
void k_ln(float* __restrict__ b0, float* __restrict__ b1,
          const float* __restrict__ lnw, const float* __restrict__ lnb)
{
    float* buf = blockIdx.y ? b1 : b0;
    int row = blockIdx.x;
    int c = threadIdx.x;
    float v = buf[(long)row * CC + c];
    float s = v, s2 = v * v;
    #pragma unroll
    for (int off = 32; off >= 1; off >>= 1) {
        s += __shfl_xor(s, off);
        s2 += __shfl_xor(s2, off);
    }
    __shared__ float red[8];
    int wid = c >> 6, lane = c & 63;
    if (lane == 0) { red[wid * 2] = s; red[wid * 2 + 1] = s2; }
    __syncthreads();
    float ts = 0.f, ts2 = 0.f;
    #pragma unroll
    for (int w = 0; w < 4; ++w) { ts += red[w * 2]; ts2 += red[w * 2 + 1]; }
    float mu = ts * (1.0f / 256.0f);
    float var = ts2 * (1.0f / 256.0f) - mu * mu;
    float rstd = 1.0f / sqrtf(var + 1e-5f);
    buf[(long)row * CC + c] = (v - mu) * rstd * lnw[c] + lnb[c];
}

// ============================================================
// 3) 128x128 f32 GEMM, 8x8 register blocking (DECISION-SAFE, proven)
// ============================================================
__global__ __launch_bounds__(256)
void k_gemm_f32_128(const float* __restrict__ A, const float* __restrict__ Wt,
                    const float* __restrict__ bias, float* __restrict__ Cout,
                    int amode, int aplane)
{
    __shared__ float As[16][136];
    __shared__ float Bs[16][136];
    const int t = threadIdx.x;
    const int m0 = blockIdx.x * 128;
    const int n0 = blockIdx.y * 128;
    const int ty = t >> 4, tx = t & 15;
    float acc[8][8] = {};
    long abase = 0; int p0 = 0;
    if (amode == 1) {
        int nb = m0 / aplane;
        p0 = m0 - nb * aplane;
        abase = (long)nb * 256 * aplane;
    }
    for (int k0 = 0; k0 < 256; k0 += 16) {
        if (amode == 0) {
            int i = t >> 1, kq = (t & 1) * 8;
            const float* ap = A + (long)(m0 + i) * 256 + k0 + kq;
            float4 a1 = *(const float4*)ap;
            float4 a2 = *(const float4*)(ap + 4);
            As[kq + 0][i] = a1.x; As[kq + 1][i] = a1.y;
            As[kq + 2][i] = a1.z; As[kq + 3][i] = a1.w;
            As[kq + 4][i] = a2.x; As[kq + 5][i] = a2.y;
            As[kq + 6][i] = a2.z; As[kq + 7][i] = a2.w;
        } else {
            int j = t >> 4, i8 = (t & 15) * 8;
            const float* ap = A + abase + (long)(k0 + j) * aplane + p0 + i8;
            *(float4*)&As[j][i8]     = *(const float4*)ap;
            *(float4*)&As[j][i8 + 4] = *(const float4*)(ap + 4);
        }
        {
            int j = t >> 4, n8 = (t & 15) * 8;
            const float* bp = Wt + (long)(k0 + j) * 256 + n0 + n8;
            *(float4*)&Bs[j][n8]     = *(const float4*)bp;
            *(float4*)&Bs[j][n8 + 4] = *(const float4*)(bp + 4);
        }
        __syncthreads();
        #pragma unroll
        for (int k = 0; k < 16; ++k) {
            float4 a1 = *(const float4*)&As[k][ty * 8];
            float4 a2 = *(const float4*)&As[k][ty * 8 + 4];
            float4 b1 = *(const float4*)&Bs[k][tx * 8];
            float4 b2 = *(const float4*)&Bs[k][tx * 8 + 4];
            float aa[8] = {a1.x, a1.y, a1.z, a1.w, a2.x, a2.y, a2.z, a2.w};
            float bb[8] = {b1.x, b1.y, b1.z, b1.w, b2.x, b2.y, b2.z, b2.w};
            #pragma unroll
            for (int ii = 0; ii < 8; ++ii)
                #pragma unroll
                for (int jj = 0; jj < 8; ++jj)
                    acc[ii][jj] = fmaf(aa[ii], bb[jj], acc[ii][jj]);
        }
        __syncthreads();
    }
    int colb = n0 + tx * 8;
    float4 bi1 = *(const float4*)(bias + colb);
    float4 bi2 = *(const float4*)(bias + colb + 4);
    float bias8[8] = {bi1.x, bi1.y, bi1.z, bi1.w, bi2.x, bi2.y, bi2.z, bi2.w};
    #pragma unroll
    for (int ii = 0; ii < 8; ++ii) {
        long mrow = m0 + ty * 8 + ii;
        float4 o1, o2;
        o1.x = acc[ii][0] + bias8[0];
        o1.y = acc[ii][1] + bias8[1];
        o1.z = acc[ii][2] + bias8[2];
        o1.w = acc[ii][3] + bias8[3];
        o2.x = acc[ii][4] + bias8[4];
        o2.y = acc[ii][5] + bias8[5];
        o2.z = acc[ii][6] + bias8[6];
        o2.w = acc[ii][7] + bias8[7];
        *(float4*)(Cout + mrow * 256 + colb) = o1;
        *(float4*)(Cout + mrow * 256 + colb + 4) = o2;
    }
}

// ============================================================
// 4) generic 64-tile f32 GEMM (kept for am: omode=1, M=6400)
// ============================================================
#define GBK 16
#define GSTR 68
__global__ __launch_bounds__(256)
void k_gemm256(const float* __restrict__ A, const float* __restrict__ Wt,
               const float* __restrict__ bias, float* __restrict__ Cout,
               int M, int amode, int aplane,
               int omode, int oplane, long obstride, int ocoff)
{
    __shared__ float As[GBK][GSTR];
    __shared__ float Bs[GBK][GSTR];
    const int t = threadIdx.x;
    const int m0 = blockIdx.x * 64;
    const int n0 = blockIdx.y * 64;
    const int ty = t >> 4, tx = t & 15;
    float acc[4][4] = {};
    long abase = 0; int p0 = 0;
    if (amode == 1) {
        int nb = m0 / aplane;
        p0 = m0 - nb * aplane;
        abase = (long)nb * 256 * aplane;
    }
    for (int k0 = 0; k0 < 256; k0 += GBK) {
        if (amode == 0) {
            int i = t >> 2, j4 = (t & 3) * 4;
            float4 a = *(const float4*)(A + (long)(m0 + i) * 256 + k0 + j4);
            As[j4 + 0][i] = a.x; As[j4 + 1][i] = a.y;
            As[j4 + 2][i] = a.z; As[j4 + 3][i] = a.w;
        } else {
            int j = t >> 4, i4 = (t & 15) * 4;
            float4 a = *(const float4*)(A + abase + (long)(k0 + j) * aplane + p0 + i4);
            *(float4*)&As[j][i4] = a;
        }
        {
            int k = t >> 4, n4 = (t & 15) * 4;
            float4 b = *(const float4*)(Wt + (long)(k0 + k) * 256 + n0 + n4);
            *(float4*)&Bs[k][n4] = b;
        }
        __syncthreads();
        #pragma unroll
        for (int k = 0; k < GBK; ++k) {
            float4 a = *(const float4*)&As[k][ty * 4];
            float4 b = *(const float4*)&Bs[k][tx * 4];
            float aa[4] = {a.x, a.y, a.z, a.w};
            float bb[4] = {b.x, b.y, b.z, b.w};
            #pragma unroll
            for (int ii = 0; ii < 4; ++ii)
                #pragma unroll
                for (int jj = 0; jj < 4; ++jj)
                    acc[ii][jj] = fmaf(aa[ii], bb[jj], acc[ii][jj]);
        }
        __syncthreads();
    }
    int colb = n0 + tx * 4;
    float4 bi = *(const float4*)(bias + colb);
    float bias4[4] = {bi.x, bi.y, bi.z, bi.w};
    if (omode == 0) {
        #pragma unroll
        for (int ii = 0; ii < 4; ++ii) {
            long mrow = m0 + ty * 4 + ii;
            float4 o;
            o.x = acc[ii][0] + bias4[0];
            o.y = acc[ii][1] + bias4[1];
            o.z = acc[ii][2] + bias4[2];
            o.w = acc[ii][3] + bias4[3];
            *(float4*)(Cout + mrow * 256 + colb) = o;
        }
    } else {
        int nb2 = m0 / oplane;
        #pragma unroll
        for (int ii = 0; ii < 4; ++ii) {
            int mrow = m0 + ty * 4 + ii;
            int p = mrow - nb2 * oplane;
            #pragma unroll
            for (int jj = 0; jj < 4; ++jj)
                Cout[(long)nb2 * obstride + (long)(ocoff + colb + jj) * oplane + p]
                    = acc[ii][jj] + bias4[jj];
        }
    }
}

// ============================================================
// 5) anchors: np-ordered 5x5 block mean (DECISION-CRITICAL)
// ============================================================
__global__ __launch_bounds__(256)
void k_anchor(const float* __restrict__ dq, const float* __restrict__ dv,
              float* __restrict__ ancq, float* __restrict__ ancv)
{
    int bs = blockIdx.x;   // b*64+s
    int c = threadIdx.x;
    int b = bs >> 6, s = bs & 63;
    int ai = s >> 3, aj = s & 7;
    float colq[5], colv[5];
    #pragma unroll
    for (int dj = 0; dj < 5; ++dj) {
        long pix0 = (long)b * CL + (ai * 5) * SWW + aj * 5 + dj;
        float cq = dq[pix0 * CC + c];
        float cv = dv[pix0 * CC + c];
        #pragma unroll
        for (int di = 1; di < 5; ++di) {
            long pix = pix0 + (long)di * SWW;
            cq = __fadd_rn(cq, dq[pix * CC + c]);
            cv = __fadd_rn(cv, dv[pix * CC + c]);
        }
        colq[dj] = cq; colv[dj] = cv;
    }
    float sq = colq[0], sv = colv[0];
    #pragma unroll
    for (int dj = 1; dj < 5; ++dj) {
        sq = __fadd_rn(sq, colq[dj]);
        sv = __fadd_rn(sv, colv[dj]);
    }
    ancq[(long)bs * CC + c] = sq / 25.0f;
    ancv[(long)bs * CC + c] = sv / 25.0f;
}

// ============================================================
// 6) attention v5: Pl-LDS broadcast replaces ds_bpermute shuffles.
//    Same accumulation order as v4 -> bit-identical output.
// ============================================================
__global__ __launch_bounds__(256)
void k_attn(const float* __restrict__ dq, const float* __restrict__ dv,
            float* __restrict__ att4)
{
    __shared__ float Kl[64][36];   // 9216 B
    __shared__ float Vl[64][36];   // 9216 B
    __shared__ float Pl[64][68];   // 17408 B, stride 68 -> group rows 4 banks apart
    int qt = blockIdx.x;     // 0..24  (64 q-rows each)
    int h = blockIdx.y;      // 0..31
    int b = head_batch(h), fc = h & 7;
    int pb = b ^ 2;
    int t = threadIdx.x;
    int qa = t >> 3, part = t & 7;
    int qrow0 = qt * 64 + qa;
    int qrow1 = qrow0 + 32;

    float qreg0[32], qreg1[32];
    {
        const float4* qp0 = (const float4*)(dq + (long)(b * CL + qrow0) * CC + fc * CSC);
        const float4* qp1 = (const float4*)(dq + (long)(b * CL + qrow1) * CC + fc * CSC);
        #pragma unroll
        for (int j8 = 0; j8 < 8; ++j8) {
            float4 f0 = qp0[j8], f1 = qp1[j8];
            qreg0[4 * j8 + 0] = f0.x; qreg0[4 * j8 + 1] = f0.y;
            qreg0[4 * j8 + 2] = f0.z; qreg0[4 * j8 + 3] = f0.w;
            qreg1[4 * j8 + 0] = f1.x; qreg1[4 * j8 + 1] = f1.y;
            qreg1[4 * j8 + 2] = f1.z; qreg1[4 * j8 + 3] = f1.w;
        }
    }
    float Oa0[4] = {0, 0, 0, 0}, Oa1[4] = {0, 0, 0, 0};
    float mr0 = -INFINITY, lr0 = 0.f;
    float mr1 = -INFINITY, lr1 = 0.f;

    int li = t >> 2, lp = t & 3;
    float4 kA, kB, vA, vB;
    {
        const float* kp = dq + (long)(pb * CL + li) * CC + fc * CSC + lp * 8;
        const float* vp = dv + (long)(pb * CL + li) * CC + fc * CSC + lp * 8;
        kA = *(const float4*)kp; kB = *(const float4*)(kp + 4);
        vA = *(const float4*)vp; vB = *(const float4*)(vp + 4);
    }

    for (int kt = 0; kt < 25; ++kt) {
        *(float4*)&Kl[li][lp * 8]     = kA;
        *(float4*)&Kl[li][lp * 8 + 4] = kB;
        *(float4*)&Vl[li][lp * 8]     = vA;
        *(float4*)&Vl[li][lp * 8 + 4] = vB;
        __syncthreads();
        if (kt + 1 < 25) {
            const float* kp = dq + (long)(pb * CL + (kt + 1) * 64 + li) * CC + fc * CSC + lp * 8;
            const float* vp = dv + (long)(pb * CL + (kt + 1) * 64 + li) * CC + fc * CSC + lp * 8;
            kA = *(const float4*)kp; kB = *(const float4*)(kp + 4);
            vA = *(const float4*)vp; vB = *(const float4*)(vp + 4);
        }
        float sc0[8], sc1[8];
        float tmax0 = -INFINITY, tmax1 = -INFINITY;
        #pragma unroll
        for (int si = 0; si < 8; ++si) {
            int s = si * 8 + part;
            const float4* kr = (const float4*)&Kl[s][0];
            float d0 = 0.f, d1 = 0.f;
            #pragma unroll
            for (int j8 = 0; j8 < 8; ++j8) {
                float4 k4 = kr[j8];
                d0 = fmaf(qreg0[4 * j8 + 0], k4.x, d0);
                d0 = fmaf(qreg0[4 * j8 + 1], k4.y, d0);
                d0 = fmaf(qreg0[4 * j8 + 2], k4.z, d0);
                d0 = fmaf(qreg0[4 * j8 + 3], k4.w, d0);
                d1 = fmaf(qreg1[4 * j8 + 0], k4.x, d1);
                d1 = fmaf(qreg1[4 * j8 + 1], k4.y, d1);
                d1 = fmaf(qreg1[4 * j8 + 2], k4.z, d1);
                d1 = fmaf(qreg1[4 * j8 + 3], k4.w, d1);
            }
            d0 *= INV_SCALE; d1 *= INV_SCALE;
            sc0[si] = d0; sc1[si] = d1;
            tmax0 = fmaxf(tmax0, d0);
            tmax1 = fmaxf(tmax1, d1);
        }
        tmax0 = fmaxf(tmax0, __shfl_xor(tmax0, 1));
        tmax0 = fmaxf(tmax0, __shfl_xor(tmax0, 2));
        tmax0 = fmaxf(tmax0, __shfl_xor(tmax0, 4));
        tmax1 = fmaxf(tmax1, __shfl_xor(tmax1, 1));
        tmax1 = fmaxf(tmax1, __shfl_xor(tmax1, 2));
        tmax1 = fmaxf(tmax1, __shfl_xor(tmax1, 4));
        float mnew0 = fmaxf(mr0, tmax0);
        float mnew1 = fmaxf(mr1, tmax1);
        float corr0 = expf(mr0 - mnew0);
        float corr1 = expf(mr1 - mnew1);
        float wexp0[8], wexp1[8];
        float psum0 = 0.f, psum1 = 0.f;
        #pragma unroll
        for (int si = 0; si < 8; ++si) {
            wexp0[si] = expf(sc0[si] - mnew0);
            psum0 += wexp0[si];
            wexp1[si] = expf(sc1[si] - mnew1);
            psum1 += wexp1[si];
        }
        psum0 += __shfl_xor(psum0, 1);
        psum0 += __shfl_xor(psum0, 2);
        psum0 += __shfl_xor(psum0, 4);
        psum1 += __shfl_xor(psum1, 1);
        psum1 += __shfl_xor(psum1, 2);
        psum1 += __shfl_xor(psum1, 4);
        lr0 = lr0 * corr0 + psum0;
        lr1 = lr1 * corr1 + psum1;
        #pragma unroll
        for (int j = 0; j < 4; ++j) { Oa0[j] *= corr0; Oa1[j] *= corr1; }
        // publish w to Pl (each 8-lane group owns rows qa and qa+32; same wave)
        #pragma unroll
        for (int si = 0; si < 8; ++si) {
            Pl[qa][si * 8 + part]      = wexp0[si];
            Pl[qa + 32][si * 8 + part] = wexp1[si];
        }
        // PV: s ascending 0..63 (same order as v4 -> bit-identical)
        #pragma unroll
        for (int s4 = 0; s4 < 16; ++s4) {
            float4 w04 = *(const float4*)&Pl[qa][s4 * 4];
            float4 w14 = *(const float4*)&Pl[qa + 32][s4 * 4];
            float w0a[4] = {w04.x, w04.y, w04.z, w04.w};
            float w1a[4] = {w14.x, w14.y, w14.z, w14.w};
            #pragma unroll
            for (int j = 0; j < 4; ++j) {
                int s = s4 * 4 + j;
                const float4 v4 = *(const float4*)&Vl[s][part * 4];
                Oa0[0] = fmaf(w0a[j], v4.x, Oa0[0]);
                Oa0[1] = fmaf(w0a[j], v4.y, Oa0[1]);
                Oa0[2] = fmaf(w0a[j], v4.z, Oa0[2]);
                Oa0[3] = fmaf(w0a[j], v4.w, Oa0[3]);
                Oa1[0] = fmaf(w1a[j], v4.x, Oa1[0]);
                Oa1[1] = fmaf(w1a[j], v4.y, Oa1[1]);
                Oa1[2] = fmaf(w1a[j], v4.z, Oa1[2]);
                Oa1[3] = fmaf(w1a[j], v4.w, Oa1[3]);
            }
        }
        mr0 = mnew0; mr1 = mnew1;
        __syncthreads();
    }
    float inv0 = 1.0f / lr0;
    float inv1 = 1.0f / lr1;
    float* op0 = att4 + (long)(b * CL + qrow0) * CC + fc * CSC + part * 4;
    float* op1 = att4 + (long)(b * CL + qrow1) * CC + fc * CSC + part * 4;
    float4 o0, o1;
    o0.x = Oa0[0] * inv0; o0.y = Oa0[1] * inv0; o0.z = Oa0[2] * inv0; o0.w = Oa0[3] * inv0;
    o1.x = Oa1[0] * inv1; o1.y = Oa1[1] * inv1; o1.z = Oa1[2] * inv1; o1.w = Oa1[3] * inv1;
    *(float4*)op0 = o0;
    *(float4*)op1 = o1;
}

// ============================================================
// 7) bilinear x4 upsample -> out[:, 0:256]
// ============================================================
__global__ __launch_bounds__(256)
void k_resize(const float* __restrict__ am, float* __restrict__ out)
{
    int plane = blockIdx.y;                       // n*256 + c
    int o = blockIdx.x * 256 + threadIdx.x;       // 0..25599
    int y = o / CW, xx = o - y * CW;
    const float* src = am + (long)plane * (SHH * SWW);
    float fy = (y + 0.5f) * 0.25f - 0.5f;
    int iy0 = (int)floorf(fy);
    float wy = fy - iy0;
    int iy1 = min(iy0 + 1, SHH - 1); iy0 = max(iy0, 0);
    float fx = (xx + 0.5f) * 0.25f - 0.5f;
    int ix0 = (int)floorf(fx);
    float wx = fx - ix0;
    int ix1 = min(ix0 + 1, SWW - 1); ix0 = max(ix0, 0);
    float v00 = src[iy0 * SWW + ix0], v01 = src[iy0 * SWW + ix1];
    float v10 = src[iy1 * SWW + ix0], v11 = src[iy1 * SWW + ix1];
    float v = (1.f - wy) * ((1.f - wx) * v00 + wx * v01)
            + wy * ((1.f - wx) * v10 + wx * v11);
    int n = plane >> 8, c = plane & 255;
    out[((long)(n * 512 + c)) * (CH * CW) + o] = v;
}

// ============================================================
// 8) precompute np-normalized anchor rows per head (DECISION-CRITICAL)
// ============================================================
__global__ __launch_bounds__(64)
void k_aqkn_np(const float* __restrict__ ancq, float* __restrict__ aqkn)
{
    int h = blockIdx.x, s = threadIdx.x;
    int b = head_batch(h), fc = h & 7;
    const float* p = ancq + (long)(b * CS + s) * CC + fc * CSC;
    float a[32];
    #pragma unroll
    for (int d = 0; d < 32; ++d) a[d] = p[d];
    float anorm = fmaxf(sqrtf(norm32_np(a)), 1e-12f);
    #pragma unroll
    for (int d = 0; d < 32; ++d) aqkn[(long)(h * CS + s) * CSC + d] = a[d] / anorm;
}

// ============================================================
// 9) routing-1 lite (DECISION-CRITICAL per-chain order)
// ============================================================
__global__ __launch_bounds__(256)
void k_routing1_lite(const float* __restrict__ dq, const float* __restrict__ aqkn,
                     const float* __restrict__ dalpha, const float* __restrict__ dbeta,
                     float* __restrict__ valb, int* __restrict__ idxb)
{
    __shared__ float An[CS * CSC];   // 8 KB
    int h = blockIdx.y;
    int b = head_batch(h), fc = h & 7;
    int t = threadIdx.x;
    for (int u = t; u < CS * CSC; u += 256) An[u] = aqkn[(long)h * CS * CSC + u];
    __syncthreads();
    int l = blockIdx.x * 256 + t;
    if (l >= CL) return;
    float da = dalpha[0], db = dbeta[0];
    const float* qp = dq + (long)(b * CL + l) * CC + fc * CSC;
    float q[32];
    #pragma unroll
    for (int d = 0; d < 32; ++d) q[d] = qp[d];
    float qnorm = fmaxf(sqrtf(norm32_np(q)), 1e-12f);
    float qn[32];
    #pragma unroll
    for (int d = 0; d < 32; ++d) qn[d] = q[d] / qnorm;
    float best = -1.f; int bi = 0;
    for (int sg = 0; sg < CS; sg += 4) {
        float acc[4];
        #pragma unroll
        for (int i = 0; i < 4; ++i) {
            const float4 a0 = *(const float4*)&An[(sg + i) * CSC];
            acc[i] = __fmul_rn(qn[0], a0.x);
            acc[i] = __fadd_rn(acc[i], __fmul_rn(qn[1], a0.y));
            acc[i] = __fadd_rn(acc[i], __fmul_rn(qn[2], a0.z));
            acc[i] = __fadd_rn(acc[i], __fmul_rn(qn[3], a0.w));
        }
        #pragma unroll
        for (int dg = 1; dg < 8; ++dg) {
            #pragma unroll
            for (int i = 0; i < 4; ++i) {
                const float4 a4 = *(const float4*)&An[(sg + i) * CSC + dg * 4];
                acc[i] = __fadd_rn(acc[i], __fmul_rn(qn[4 * dg + 0], a4.x));
                acc[i] = __fadd_rn(acc[i], __fmul_rn(qn[4 * dg + 1], a4.y));
                acc[i] = __fadd_rn(acc[i], __fmul_rn(qn[4 * dg + 2], a4.z));
                acc[i] = __fadd_rn(acc[i], __fmul_rn(qn[4 * dg + 3], a4.w));
            }
        }
        #pragma unroll
        for (int i = 0; i < 4; ++i) {
            float tv = __fadd_rn(__fmul_rn(da, acc[i]), db);
            float sim = 1.0f / (1.0f + expf(-tv));
            if (sim > best) { best = sim; bi = sg + i; }
        }
    }
    valb[h * CL + l] = best;
    idxb[h * CL + l] = bi;
}

// ============================================================
// 10) deterministic scatter (DECISION/VALUE path)
// ============================================================
__global__ __launch_bounds__(64)
void k_scatter(const float* __restrict__ dq, const float* __restrict__ dv,
               const float* __restrict__ ancq, const float* __restrict__ ancv,
               const float* __restrict__ valb, const int* __restrict__ idxb,
               float* __restrict__ agg)
{
    int cl = blockIdx.x;
    int h = cl >> 6, s = cl & 63;
    int b = head_batch(h), fc = h & 7;
    int j = threadIdx.x;
    const float* base = (j < 32) ? (dq + (long)b * CL * CC + fc * CSC + j)
                                 : (dv + (long)b * CL * CC + fc * CSC + (j - 32));
    float init = (j < 32) ? ancq[(long)(b * CS + s) * CC + fc * CSC + j]
                          : ancv[(long)(b * CS + s) * CC + fc * CSC + (j - 32)];
    float acc = init, cnt = 1.0f;
    const int* ix = idxb + h * CL;
    const float* vb = valb + h * CL;
    for (int l = 0; l < CL; ++l) {
        if (ix[l] == s) {
            float v = vb[l];
            acc = __fadd_rn(acc, __fmul_rn(v, base[(long)l * CC]));
            cnt = __fadd_rn(cnt, v);
        }
    }
    agg[(long)cl * 65 + j] = acc;
    if (j == 0) agg[(long)cl * 65 + 64] = cnt;
}

// ============================================================
// 11) finalize (DECISION-CRITICAL)
// ============================================================
__global__ __launch_bounds__(64)
void k_finalize(const float* __restrict__ agg, float* __restrict__ apn,
                float* __restrict__ avo)
{
    int h = blockIdx.x, s = threadIdx.x;
    int sh_ = h ^ 16;
    const float* r = agg + (long)(sh_ * CS + s) * 65;
    float cnt = r[64];
    float a[32];
    #pragma unroll
    for (int d = 0; d < 32; ++d) a[d] = r[d] / cnt;
    float nrm = fmaxf(sqrtf(norm32_np(a)), 1e-12f);
    long o = (long)(h * CS + s) * CSC;
    #pragma unroll
    for (int d = 0; d < 32; ++d) {
        apn[o + d] = a[d] / nrm;
        avo[o + d] = r[32 + d] / cnt;
    }
}

// ============================================================
// 12) routing-2 lite (DECISION-CRITICAL per-chain order)
// ============================================================
__global__ __launch_bounds__(512)
void k_routing2_lite(float* __restrict__ xp, const float* __restrict__ apn,
                     const float* __restrict__ avv,
                     const float* __restrict__ alpha_, const float* __restrict__ beta_)
{
    __shared__ float Anl[16384];   // [s][dg][fc][4]  64 KB
    int blk = blockIdx.x;          // 1600
    int b = blk / 400;
    int p0 = (blk % 400) * 64;
    int t = threadIdx.x;
    int pi = t >> 3, fc = t & 7;
    int p = p0 + pi;
    int hb0 = ((b >> 1) << 4) | ((b & 1) << 3);
    float al = alpha_[0], be = beta_[0];
    for (int u = t; u < 16384; u += 512) {
        int fci = u >> 11, s = (u >> 5) & 63, d = u & 31;
        Anl[((s * 8 + (d >> 2)) * 8 + fci) * 4 + (d & 3)] = apn[(long)hb0 * 2048 + u];
    }
    __syncthreads();
    float* xr = xp + ((long)b * 25600 + p) * CC + fc * CSC;
    float q[32];
    #pragma unroll
    for (int j8 = 0; j8 < 8; ++j8) {
        float4 f = ((const float4*)xr)[j8];
        q[4 * j8 + 0] = f.x; q[4 * j8 + 1] = f.y;
        q[4 * j8 + 2] = f.z; q[4 * j8 + 3] = f.w;
    }
    float qnorm = fmaxf(sqrtf(norm32_np(q)), 1e-12f);
    float qn[32];
    #pragma unroll
    for (int d = 0; d < 32; ++d) qn[d] = q[d] / qnorm;

    float best = -1.f; int bi = 0;
    for (int sg = 0; sg < CS; sg += 4) {
        float acc[4];
        #pragma unroll
        for (int i = 0; i < 4; ++i) {
            const float4 a0 = *(const float4*)&Anl[(((sg + i) * 8 + 0) * 8 + fc) * 4];
            acc[i] = __fmul_rn(qn[0], a0.x);
            acc[i] = __fadd_rn(acc[i], __fmul_rn(qn[1], a0.y));
            acc[i] = __fadd_rn(acc[i], __fmul_rn(qn[2], a0.z));
            acc[i] = __fadd_rn(acc[i], __fmul_rn(qn[3], a0.w));
        }
        #pragma unroll
        for (int dg = 1; dg < 8; ++dg) {
            #pragma unroll
            for (int i = 0; i < 4; ++i) {
                const float4 a4 = *(const float4*)&Anl[(((sg + i) * 8 + dg) * 8 + fc) * 4];
                acc[i] = __fadd_rn(acc[i], __fmul_rn(qn[4 * dg + 0], a4.x));
                acc[i] = __fadd_rn(acc[i], __fmul_rn(qn[4 * dg + 1], a4.y));
                acc[i] = __fadd_rn(acc[i], __fmul_rn(qn[4 * dg + 2], a4.z));
                acc[i] = __fadd_rn(acc[i], __fmul_rn(qn[4 * dg + 3], a4.w));
            }
        }
        #pragma unroll
        for (int i = 0; i < 4; ++i) {
            float tv = __fadd_rn(__fmul_rn(al, acc[i]), be);
            float sim = 1.0f / (1.0f + expf(-tv));
            if (sim > best) { best = sim; bi = sg + i; }
        }
    }
    const float* av = avv + ((long)(hb0 + fc) * CS + bi) * CSC;
    #pragma unroll
    for (int d = 0; d < 32; ++d) xr[d] = __fmul_rn(best, av[d]);
}

// ============================================================
// 13) w_m1 -> bf16 transposed [n][k] (one-time, tiny)
// ============================================================
__global__ __launch_bounds__(256)
void k_wm1t_bf16(const float* __restrict__ wm1, short* __restrict__ wt)
{
    int n = blockIdx.x;       // 256
    int k = threadIdx.x;      // 256
    wt[n * 256 + k] = f2bf(wm1[k * 256 + n]);
}

// ============================================================
// 14) final coc GEMM in bf16 MFMA (tolerance path)
// ============================================================
__global__ __launch_bounds__(256)
void k_gemm_bf16_final(const float* __restrict__ coc, const short* __restrict__ wt,
                       const float* __restrict__ bias, float* __restrict__ out)
{
    __shared__ short As[64][40];
    __shared__ short Bs[64][40];
    const int t = threadIdx.x;
    const int m0 = blockIdx.x * 64;
    const int n0 = blockIdx.y * 64;
    const int nb = m0 / 25600;
    const int p0 = m0 - nb * 25600;
    const int w = t >> 6;
    const int l = t & 63;
    const int lr = l & 15, lk = l >> 4;

    f32x4 acc[4] = {};
    for (int k0 = 0; k0 < 256; k0 += 32) {
        {
            int row = t >> 2, kq = (t & 3) * 8;
            const float* ap = coc + (long)(m0 + row) * 256 + k0 + kq;
            float4 a1 = *(const float4*)ap;
            float4 a2 = *(const float4*)(ap + 4);
            bf16x8 v;
            v[0] = f2bf(a1.x); v[1] = f2bf(a1.y); v[2] = f2bf(a1.z); v[3] = f2bf(a1.w);
            v[4] = f2bf(a2.x); v[5] = f2bf(a2.y); v[6] = f2bf(a2.z); v[7] = f2bf(a2.w);
            *(bf16x8*)&As[row][kq] = v;
        }
        {
            int col = t >> 2, kq = (t & 3) * 8;
            bf16x8 v = *(const bf16x8*)&wt[(n0 + col) * 256 + k0 + kq];
            *(bf16x8*)&Bs[col][kq] = v;
        }
        __syncthreads();
        bf16x8 af = *(const bf16x8*)&As[w * 16 + lr][lk * 8];
        #pragma unroll
        for (int c = 0; c < 4; ++c) {
            bf16x8 bfv = *(const bf16x8*)&Bs[c * 16 + lr][lk * 8];
            acc[c] = __builtin_amdgcn_mfma_f32_16x16x32_bf16(af, bfv, acc[c], 0, 0, 0);
        }
        __syncthreads();
    }
    #pragma unroll
    for (int c = 0; c < 4; ++c) {
        int col = n0 + c * 16 + lr;
        float bv = bias[col];
        #pragma unroll
        for (int r = 0; r < 4; ++r) {
            int p = p0 + w * 16 + lk * 4 + r;
            out[(long)nb * 13107200 + (long)(256 + col) * 25600 + p] = acc[c][r] + bv;
        }
    }
}

// ============================================================
// launcher
// ============================================================
extern "C" void kernel_launch(void* const* d_in, const int* in_sizes, int n_in,
                              void* d_out, int out_size, void* d_ws, size_t ws_size,
                              hipStream_t stream)
{
    const float* x      = (const float*)d_in[0];
    const float* wdw    = (const float*)d_in[1];
    const float* bdw    = (const float*)d_in[2];
    const float* lnw    = (const float*)d_in[3];
    const float* lnb    = (const float*)d_in[4];
    const float* wqk    = (const float*)d_in[5];
    const float* bqk    = (const float*)d_in[6];
    const float* wv     = (const float*)d_in[7];
    const float* bv     = (const float*)d_in[8];
    const float* wpoint = (const float*)d_in[9];
    const float* bpoint = (const float*)d_in[10];
    const float* dalpha = (const float*)d_in[11];
    const float* dbeta  = (const float*)d_in[12];
    const float* alpha_ = (const float*)d_in[13];
    const float* beta_  = (const float*)d_in[14];
    const float* wm0    = (const float*)d_in[15];
    const float* bm0    = (const float*)d_in[16];
    const float* wm1    = (const float*)d_in[17];
    const float* bm1    = (const float*)d_in[18];
    float* out = (float*)d_out;
    float* ws = (float*)d_ws;

    float* dqn  = ws;                 // 1,638,400
    float* dvn  = ws + 1638400;       // 1,638,400
    float* dq   = ws + 3276800;       // 1,638,400
    float* dv   = ws + 4915200;       // 1,638,400
    float* ancq = ws + 6553600;       // 65,536
    float* ancv = ws + 6619136;       // 65,536
    float* aqkn = ws + 6684672;       // 65,536
    float* agg  = ws + 6750208;       // 133,120
    float* apn  = ws + 6883328;       // 65,536
    float* avv  = ws + 6948864;       // 65,536
    float* valb = ws + 7014400;       // 51,200
    int*   idxb = (int*)(ws + 7065600); // 51,200
    short* wt   = (short*)(ws + 7116800); // 65,536 shorts
    float* xp   = ws + 7149568;       // 26,214,400  (becomes coc in place)
    float* att4 = dqn;                // reuse after dq GEMM consumed dqn
    float* am   = dvn;                // reuse after dv GEMM consumed dvn

    // --- shared upstream (frozen conv/LN; proven 128-tile GEMM) ---
    k_conv_pool<<<dim3(CN * CL), dim3(256), 0, stream>>>(x, wdw, bdw, dqn, dvn);
    k_ln<<<dim3(CN * CL, 2), dim3(256), 0, stream>>>(dqn, dvn, lnw, lnb);
    k_gemm_f32_128<<<dim3(50, 2), dim3(256), 0, stream>>>(dqn, wqk, bqk, dq, 0, 0);
    k_gemm_f32_128<<<dim3(50, 2), dim3(256), 0, stream>>>(dvn, wv,  bv,  dv, 0, 0);
    k_anchor<<<dim3(CN * CS), dim3(256), 0, stream>>>(dq, dv, ancq, ancv);

    // --- att half ---
    k_attn<<<dim3(25, NHEAD), dim3(256), 0, stream>>>(dq, dv, att4);
    k_gemm256<<<dim3(100, 4), dim3(256), 0, stream>>>(att4, wm0, bm0, am, 6400, 0, 0,
                                                      1, 1600, 409600L, 0);
    k_resize<<<dim3(100, CN * 256), dim3(256), 0, stream>>>(am, out);

    // --- coc half (np-matched decision arithmetic) ---
    k_aqkn_np<<<dim3(NHEAD), dim3(64), 0, stream>>>(ancq, aqkn);
    k_routing1_lite<<<dim3(7, NHEAD), dim3(256), 0, stream>>>(dq, aqkn, dalpha, dbeta,
                                                              valb, idxb);
    k_scatter<<<dim3(2048), dim3(64), 0, stream>>>(dq, dv, ancq, ancv, valb, idxb, agg);
    k_finalize<<<dim3(NHEAD), dim3(64), 0, stream>>>(agg, apn, avv);
    k_gemm_f32_128<<<dim3(800, 2), dim3(256), 0, stream>>>(x, wpoint, bpoint, xp, 1, 25600);
    k_routing2_lite<<<dim3(1600), dim3(512), 0, stream>>>(xp, apn, avv, alpha_, beta_);
    k_wm1t_bf16<<<dim3(256), dim3(256), 0, stream>>>(wm1, wt);
    k_gemm_bf16_final<<<dim3(1600, 4), dim3(256), 0, stream>>>(xp, wt, bm1, out);
}